// Round 7
// baseline (48.647 us; speedup 1.0000x reference)
//
#include <hip/hip_runtime.h>

#define NB 512
#define NATOMS 1024
#define NG 256
#define NL 8
#define NK 128

#define KBT 0.59616123f            // 0.0019872041 * 300
#define ALPHA_C 10.0f
#define LN2 0.6931471805599453f
#define LOG2E 1.4426950408889634f
#define INV2BW2 22.222221f         // 1/(2*0.15^2)
#define SCALE2 (INV2BW2 * LOG2E)   // log2-domain scale
#define LOG_NORM (-1.0170649f)     // log(128) + 3*log(2*pi*BW^2)

#define WL_CAP 2048                // max active (g,l) pairs = NG*NL
#define FILL_BLOCKS 128            // 128*256*16B = 512 KiB = NG*NB*4B exactly

__device__ __forceinline__ float fexp2(float x) { return __builtin_amdgcn_exp2f(x); }
__device__ __forceinline__ float flog2(float x) { return __builtin_amdgcn_logf(x); }

// monotone float<->uint key (unsigned order == float order), for atomicMin
__device__ __forceinline__ unsigned fkey(float f) {
  unsigned u = __float_as_uint(f);
  return (u & 0x80000000u) ? ~u : (u | 0x80000000u);
}
__device__ __forceinline__ float funkey(unsigned k) {
  unsigned u = (k & 0x80000000u) ? (k ^ 0x80000000u) : ~k;
  return __uint_as_float(u);
}

__device__ __forceinline__ float wred_min(float v) {
#pragma unroll
  for (int m = 32; m >= 1; m >>= 1) v = fminf(v, __shfl_xor(v, m, 64));
  return v;
}
__device__ __forceinline__ float wred_sum(float v) {
#pragma unroll
  for (int m = 32; m >= 1; m >>= 1) v += __shfl_xor(v, m, 64);
  return v;
}

// Grid = 1 + FILL_BLOCKS.  Block 0: prefix-sum nl over the 256 groups ->
// packed worklist of active (g,l) pairs (wl[WL_CAP] = count).  Blocks
// 1..FILL_BLOCKS: fill gmin_u with 0xFFFFFFFF (full 512 KiB).
__global__ __launch_bounds__(256) void build_worklist(
    const int* __restrict__ gsizes, int* __restrict__ wl,
    uint4* __restrict__ gmin_u4) {
  const int t = threadIdx.x;
  if (blockIdx.x != 0) {
    const unsigned F = 0xFFFFFFFFu;
    gmin_u4[(blockIdx.x - 1) * 256 + t] = make_uint4(F, F, F, F);
    return;
  }
  const int lane = t & 63, wid = t >> 6;
  int gs = gsizes[t];
  int nl = gs < 1 ? 1 : (gs > NL ? NL : gs);
  int x = nl;                       // inclusive scan within wave
#pragma unroll
  for (int m = 1; m < 64; m <<= 1) {
    int y = __shfl_up(x, m, 64);
    if (lane >= m) x += y;
  }
  __shared__ int wsum[4];
  if (lane == 63) wsum[wid] = x;
  __syncthreads();
  int off = 0;
  for (int i = 0; i < wid; ++i) off += wsum[i];
  int inc = off + x, exc = inc - nl;
  for (int j = 0; j < nl; ++j) wl[exc + j] = (t << 3) | j;
  if (t == 255) wl[WL_CAP] = inc;   // total active pairs
}

// Block = TWO worklist entries (128 threads each).  Thread li (0..127) of an
// entry owns 4 b's: b = j*128 + li, j=0..3 -- amortizing each LDS tab read
// over 4 batches (round-6 profile: stage1 was LDS-BW-bound at 3.86 GB of
// ds_read_b128 traffic; this cuts it 4x).  LSE: one online chain per b,
// merging groups of 4 k's (1.5 exp/k).  All in log2 domain.
__global__ __launch_bounds__(256) void stage1_kernel(
    const float* __restrict__ positions, const float* __restrict__ kde,
    const float* __restrict__ weight, const float* __restrict__ offs,
    const int* __restrict__ atom_idxs, const int* __restrict__ wl,
    unsigned* __restrict__ gmin_u) {
  const int bid = blockIdx.x;
  const int count = wl[WL_CAP];
  if ((bid << 1) >= count) return;      // fully-dead block: uniform exit

  const int t = threadIdx.x;
  const int ep = t >> 7;                // entry half (0/1)
  const int li = t & 127;               // lane within entry
  const int w = (bid << 1) + ep;
  const bool active = (w < count);

  __shared__ __align__(16) float tab[2][NK][8];   // [mu'0..5, h, pad]

  int gl = 0;
  if (active) {
    const int e = wl[w];
    gl = (e >> 3) * NL + (e & 7);
    const float* mp = kde + (size_t)gl * NK * 6 + (size_t)li * 6;
    float m0 = mp[0], m1 = mp[1], m2 = mp[2], m3 = mp[3], m4 = mp[4], m5 = mp[5];
    float mu2 = m0 * m0 + m1 * m1 + m2 * m2 + m3 * m3 + m4 * m4 + m5 * m5;
    const float cf = 2.0f * SCALE2;
    *reinterpret_cast<float4*>(&tab[ep][li][0]) =
        make_float4(m0 * cf, m1 * cf, m2 * cf, m3 * cf);
    *reinterpret_cast<float4*>(&tab[ep][li][4]) =
        make_float4(m4 * cf, m5 * cf, -mu2 * SCALE2, 0.0f);
  }
  __syncthreads();                      // all waves reach this, then inactive exit
  if (!active) return;

  // gather positions + distances for my 4 b's
  const int4 idx = *reinterpret_cast<const int4*>(atom_idxs + (gl << 2));
  const int ids[4] = {idx.x, idx.y, idx.z, idx.w};
  const int PI_[6] = {0, 0, 0, 1, 1, 2};
  const int PJ_[6] = {1, 2, 3, 2, 3, 3};
  float d[4][6], c2[4];
#pragma unroll
  for (int j = 0; j < 4; ++j) {
    const int b = (j << 7) + li;
    const float* pb = positions + (size_t)b * NATOMS * 3;
    float ax[4], ay[4], az[4];
#pragma unroll
    for (int a = 0; a < 4; ++a) {
      const float* pp = pb + ids[a] * 3;
      ax[a] = pp[0]; ay[a] = pp[1]; az[a] = pp[2];
    }
    float x2 = 0.0f;
#pragma unroll
    for (int q = 0; q < 6; ++q) {
      float dx = ax[PI_[q]] - ax[PJ_[q]];
      float dy = ay[PI_[q]] - ay[PJ_[q]];
      float dz = az[PI_[q]] - az[PJ_[q]];
      float dd = dx * dx + dy * dy + dz * dz + 1e-12f;
      d[j][q] = sqrtf(dd);
      x2 += d[j][q] * d[j][q];
    }
    c2[j] = -x2 * SCALE2;               // constant over k (log2 domain)
  }

  // online LSE over K: one chain per b, 4-k merge groups
  float m_[4] = {-1e30f, -1e30f, -1e30f, -1e30f};
  float s_[4] = {0.0f, 0.0f, 0.0f, 0.0f};
  for (int k0 = 0; k0 < NK; k0 += 4) {
    float4 A[4], Bv[4];
#pragma unroll
    for (int i = 0; i < 4; ++i) {
      const float4* r = reinterpret_cast<const float4*>(&tab[ep][k0 + i][0]);
      A[i] = r[0]; Bv[i] = r[1];
    }
#pragma unroll
    for (int j = 0; j < 4; ++j) {
      float v[4];
#pragma unroll
      for (int i = 0; i < 4; ++i) {
        float vv = Bv[i].z;
        vv = fmaf(A[i].x, d[j][0], vv);
        vv = fmaf(A[i].y, d[j][1], vv);
        vv = fmaf(A[i].z, d[j][2], vv);
        vv = fmaf(A[i].w, d[j][3], vv);
        vv = fmaf(Bv[i].x, d[j][4], vv);
        vv = fmaf(Bv[i].y, d[j][5], vv);
        v[i] = vv;
      }
      float gm = fmaxf(fmaxf(v[0], v[1]), fmaxf(v[2], v[3]));
      float p = fexp2(v[0] - gm) + fexp2(v[1] - gm)
              + fexp2(v[2] - gm) + fexp2(v[3] - gm);
      float nm = fmaxf(m_[j], gm);
      s_[j] = fmaf(s_[j], fexp2(m_[j] - nm), p * fexp2(gm - nm));
      m_[j] = nm;
    }
  }

  const float wgt = weight[gl], off = offs[gl];
  const int g = gl >> 3;                // gl / NL
#pragma unroll
  for (int j = 0; j < 4; ++j) {
    float lse2 = c2[j] + m_[j] + flog2(s_[j]);
    float logP = lse2 * LN2 - LOG_NORM;
    float scaled = -KBT * logP * wgt + off;
    atomicMin(&gmin_u[g * NB + (j << 7) + li], fkey(scaled));
  }
}

// One block per b: min over g, then logsumexp(-ALPHA*gmin) over g.
__global__ __launch_bounds__(256) void stage2_kernel(
    const unsigned* __restrict__ gmin_u, float* __restrict__ out) {
  const int b = blockIdx.x;
  const int t = threadIdx.x;
  const int lane = t & 63;
  const int wid = t >> 6;
  float v = funkey(gmin_u[t * NB + b]);
  __shared__ float sm[4], ss[4];
  float m = wred_min(v);
  if (lane == 0) sm[wid] = m;
  __syncthreads();
  float M = fminf(fminf(sm[0], sm[1]), fminf(sm[2], sm[3]));
  float e = fexp2(-ALPHA_C * LOG2E * (v - M));
  float s = wred_sum(e);
  if (lane == 0) ss[wid] = s;
  __syncthreads();
  if (t == 0) {
    float S = ss[0] + ss[1] + ss[2] + ss[3];
    out[b] = M - flog2(S) * LN2 / ALPHA_C;
  }
}

extern "C" void kernel_launch(void* const* d_in, const int* in_sizes, int n_in,
                              void* d_out, int out_size, void* d_ws, size_t ws_size,
                              hipStream_t stream) {
  const float* positions = (const float*)d_in[0];
  const float* kde       = (const float*)d_in[1];
  const float* weight    = (const float*)d_in[2];
  const float* offs      = (const float*)d_in[3];
  const int*   atom_idxs = (const int*)d_in[4];
  const int*   gsizes    = (const int*)d_in[5];
  float* out = (float*)d_out;

  unsigned* gmin_u = (unsigned*)d_ws;                 // NG*NB u32 = 512 KiB
  int* wl = (int*)d_ws + (size_t)NG * NB;             // WL_CAP+1 ints (~8 KiB)

  build_worklist<<<dim3(1 + FILL_BLOCKS), dim3(256), 0, stream>>>(
      gsizes, wl, (uint4*)gmin_u);
  stage1_kernel<<<dim3(WL_CAP / 2), dim3(256), 0, stream>>>(
      positions, kde, weight, offs, atom_idxs, wl, gmin_u);
  stage2_kernel<<<dim3(NB), dim3(256), 0, stream>>>(gmin_u, out);
}